// Round 7
// baseline (226.819 us; speedup 1.0000x reference)
//
#include <hip/hip_runtime.h>
#include <stdint.h>

// YatCausalAttention on MI355X (gfx950).
// Inputs FP32, output FP32. Intermediates FP16 via f16 MFMA, fp32 accum.
// Pipeline: cvt_x -> transpose+cvt weights -> gemm<128>(x,wqkvT) -> qkv(fp16)
//           -> yat flash attention (128-row Q-blocks) -> gemm<64> -> out.
// ws (fp16 elems): wqkvT 3072*1024 | woT 1024*1024 | qkv 4096*3072 | xh/attn 4096*1024 = 40 MB
// R7: (a) yat rewritten: 512-thread blocks own 128 q-rows; each 64-key K/V tile
// staged once per 128 queries (halves staging VALU + barriers per score).
// Causal diag spans 2 key-tiles (kdiff mask). Q-frags hoisted. CU-balanced yb map.
// (b) gemm2 retiled 128x64 -> 512 blocks = 2/CU (was 256 = 1/CU latency-bound).

#define TSEQ 2048
#define BATCH 2

typedef _Float16 f16x8 __attribute__((ext_vector_type(8)));
typedef float f32x4 __attribute__((ext_vector_type(4)));

#define MFMA16(a, b, c) __builtin_amdgcn_mfma_f32_16x16x32_f16(a, b, c, 0, 0, 0)

__device__ __forceinline__ unsigned short f2h(float f) {
  union { _Float16 h; unsigned short u; } v;
  v.h = (_Float16)f;
  return v.u;
}
__device__ __forceinline__ float h2f(unsigned short u) {
  union { unsigned short u; _Float16 h; } v;
  v.u = u;
  return (float)v.h;
}
__device__ __forceinline__ unsigned int pack2h(float lo, float hi) {
  return (unsigned int)f2h(lo) | ((unsigned int)f2h(hi) << 16);
}
__device__ __forceinline__ float sumsq_u32(unsigned int u) {
  float lo = h2f(u & 0xffffu);
  float hi = h2f(u >> 16);
  return lo * lo + hi * hi;
}
__device__ __forceinline__ void async_ld16(const void* g, const void* l) {
  __builtin_amdgcn_global_load_lds((const __attribute__((address_space(1))) void*)g,
                                   (__attribute__((address_space(3))) void*)l,
                                   16, 0, 0);
}

// ---------------- x: fp32 -> fp16, 8 elems/thread ----------------
__global__ __launch_bounds__(256) void cvt_x(const float* __restrict__ src,
                                             unsigned short* __restrict__ dst) {
  const int i = (blockIdx.x * 256 + threadIdx.x) * 8;
  const float4 a = *(const float4*)(src + i);
  const float4 b = *(const float4*)(src + i + 4);
  uint4 o;
  o.x = pack2h(a.x, a.y); o.y = pack2h(a.z, a.w);
  o.z = pack2h(b.x, b.y); o.w = pack2h(b.z, b.w);
  *(uint4*)(dst + i) = o;
}

// ------------- weight transpose+convert: src[K][N] (fp32) -> dst[N][K] (fp16) -------------
__global__ __launch_bounds__(256) void transpose_w(const float* __restrict__ src,
                                                   unsigned short* __restrict__ dst,
                                                   int K, int N) {
  __shared__ unsigned short tile[32][33];
  const int tx = threadIdx.x, ty = threadIdx.y;           // (32,8)
  const int nb = blockIdx.x * 32, kb = blockIdx.y * 32;
#pragma unroll
  for (int i = 0; i < 4; i++)
    tile[ty + 8 * i][tx] = f2h(src[(size_t)(kb + ty + 8 * i) * N + nb + tx]);
  __syncthreads();
#pragma unroll
  for (int i = 0; i < 4; i++)
    dst[(size_t)(nb + ty + 8 * i) * K + kb + tx] = tile[tx][ty + 8 * i];
}

// ------------- C[M][TN-tile] = A[M][K] * Bt[N][K]^T + bias[N]  (fp16 in, fp32 acc) -------------
// 128xTN tile, BK=32, global_load_lds width=16. TN=128: wave=64x64 (4x4 MFMA).
// TN=64: wave=64x32 (4x2 MFMA), grid doubles -> 2 blocks/CU for small-N gemm.
template <int TN, bool OUT_F32>
__global__ __launch_bounds__(256) void gemm_bt(const unsigned short* __restrict__ A,
                                               const unsigned short* __restrict__ Bt,
                                               const float* __restrict__ bias,
                                               void* __restrict__ Cp,
                                               int N, int K) {
  __shared__ __attribute__((aligned(16))) unsigned short Atile[128 * 32];
  __shared__ __attribute__((aligned(16))) unsigned short Btile[TN * 32];
  constexpr int NJ = TN / 32;  // 16-col tiles per wave
  const int tid = threadIdx.x;
  const int w = tid >> 6, lane = tid & 63;
  const int quad = lane >> 4, l15 = lane & 15;
  const int m0 = blockIdx.y * 128, n0 = blockIdx.x * TN;
  const int wr = w >> 1, wc = w & 1;
  const int nwc = wc * (TN / 2);
  f32x4 acc[4][NJ] = {};
  for (int kt = 0; kt < K; kt += 32) {
    __syncthreads();  // previous iteration's fragment reads complete
#pragma unroll
    for (int it = 0; it < 2; it++) {      // A: 128 rows
      const int c = it * 256 + tid;       // chunk: row = c>>2, 8-elem k-chunk = c&3
      async_ld16(A + (size_t)(m0 + (c >> 2)) * K + kt + (c & 3) * 8,
                 &Atile[(size_t)(it * 256 + w * 64) * 8]);   // wave-uniform LDS base
    }
#pragma unroll
    for (int it = 0; it < TN / 64; it++) {  // B: TN rows
      const int c = it * 256 + tid;
      async_ld16(Bt + (size_t)(n0 + (c >> 2)) * K + kt + (c & 3) * 8,
                 &Btile[(size_t)(it * 256 + w * 64) * 8]);
    }
    __syncthreads();  // vmcnt(0) drain lands the async copies
    f16x8 af[4], bfr[NJ];
#pragma unroll
    for (int i = 0; i < 4; i++)
      af[i] = *(const f16x8*)&Atile[(wr * 64 + i * 16 + l15) * 32 + quad * 8];
#pragma unroll
    for (int j = 0; j < NJ; j++)
      bfr[j] = *(const f16x8*)&Btile[(nwc + j * 16 + l15) * 32 + quad * 8];
#pragma unroll
    for (int i = 0; i < 4; i++)
#pragma unroll
      for (int j = 0; j < NJ; j++)
        acc[i][j] = MFMA16(af[i], bfr[j], acc[i][j]);
  }
  // epilogue: C/D layout col=lane&15, row=quad*4+reg
#pragma unroll
  for (int j = 0; j < NJ; j++) {
    const int n = n0 + nwc + j * 16 + l15;
    const float bv = bias[n];
#pragma unroll
    for (int i = 0; i < 4; i++) {
      const int mb = m0 + wr * 64 + i * 16 + quad * 4;
#pragma unroll
      for (int r = 0; r < 4; r++) {
        if constexpr (OUT_F32)
          ((float*)Cp)[(size_t)(mb + r) * N + n] = acc[i][j][r] + bv;
        else
          ((unsigned short*)Cp)[(size_t)(mb + r) * N + n] = f2h(acc[i][j][r] + bv);
      }
    }
  }
}

// ---------------- Yat causal flash attention (fp16 in/out, fp32 math) ----------------
// grid: (B*H=32, 16). Block 512 = 8 waves owns 128 q-rows; wave w: rows [16w,16w+16).
// Each 64-key K/V tile staged ONCE per 128 queries. kt = 0..2*yb+1; causal mask
// kdiff = kt*64 - yb*128 in {0,64} on the last two tiles. K/V prefetched 1 iter ahead.
__global__ __launch_bounds__(512, 4) void yat_attn(const unsigned short* __restrict__ qkv,
                                                   unsigned short* __restrict__ outp) {
  __shared__ __attribute__((aligned(16))) unsigned short Qp[128 * 72];  // [q][d] pad 72
  __shared__ __attribute__((aligned(16))) unsigned short Kp[64 * 72];   // [t][d]
  __shared__ __attribute__((aligned(16))) unsigned short Vt[64 * 72];   // [d][t]
  __shared__ __attribute__((aligned(16))) unsigned short Pl[128 * 72];  // [q][t]
  __shared__ float qsq[128], ksq[64], bcast[128];
  const int tid = threadIdx.x;
  const int w = tid >> 6, lane = tid & 63;
  const int quad = lane >> 4, l15 = lane & 15;
  const int bh = blockIdx.x, b = bh >> 4, h = bh & 15;
  // CU-balanced map: CU hosts y and y+8 -> iters (32-2y)+(2y+2) = 34 for all y.
  const int y = blockIdx.y;
  const int yb = (y < 8) ? 15 - y : y - 8;
  const int ktmax = 2 * yb + 1;
  const unsigned short* base = qkv + (size_t)b * TSEQ * 3072 + h * 64;
  const int t2 = tid >> 2, dc = (tid & 3) * 16;   // Q staging: 128 rows x 16 d
  const int tk = tid >> 3, dck = (tid & 7) * 8;   // K staging: 64 rows x 8 d
  const int d0 = tid & 31, tg4 = tid >> 5;        // V staging: 2 d-rows x 4 t

  {  // stage Q tile + row sums of squares (same rounded values MFMA sees)
    const unsigned short* g = base + (size_t)(yb * 128 + t2) * 3072 + dc;
    uint4 v0 = *(const uint4*)g;
    uint4 v1 = *(const uint4*)(g + 8);
    *(uint4*)&Qp[t2 * 72 + dc] = v0;
    *(uint4*)&Qp[t2 * 72 + dc + 8] = v1;
    float s = sumsq_u32(v0.x) + sumsq_u32(v0.y) + sumsq_u32(v0.z) + sumsq_u32(v0.w) +
              sumsq_u32(v1.x) + sumsq_u32(v1.y) + sumsq_u32(v1.z) + sumsq_u32(v1.w);
    s += __shfl_xor(s, 1);
    s += __shfl_xor(s, 2);
    if ((tid & 3) == 0) qsq[t2] = s;
  }
  __syncthreads();
  // hoisted loop-invariant Q fragments (wave w, q rows 16w..16w+16)
  const f16x8 aq0 = *(const f16x8*)&Qp[(w * 16 + l15) * 72 + quad * 8];
  const f16x8 aq1 = *(const f16x8*)&Qp[(w * 16 + l15) * 72 + 32 + quad * 8];

  f32x4 accO[4] = {};                    // O^T: lane q = 16w+l15, d = 16i+quad*4+r
  float m_r[4] = {0.f, 0.f, 0.f, 0.f};   // scores >= 0 so 0 is a valid init max
  float l_r[4] = {0.f, 0.f, 0.f, 0.f};

  // prefetch kt=0 K/V into registers
  uint4 kreg;
  unsigned int vreg[4];
  {
    kreg = *(const uint4*)(base + 1024 + (size_t)tk * 3072 + dck);
    const unsigned short* gv = base + 2048 + (size_t)(tg4 * 4) * 3072 + 2 * d0;
#pragma unroll
    for (int s = 0; s < 4; s++)
      vreg[s] = *(const unsigned int*)(gv + (size_t)s * 3072);
  }

  for (int kt = 0; kt <= ktmax; kt++) {
    __syncthreads();  // prev iteration's Kp/Vt/Pl reads complete
    {  // commit staged K [t][d] + ksq from registers
      *(uint4*)&Kp[tk * 72 + dck] = kreg;
      float s = sumsq_u32(kreg.x) + sumsq_u32(kreg.y) + sumsq_u32(kreg.z) +
                sumsq_u32(kreg.w);
      s += __shfl_xor(s, 1);
      s += __shfl_xor(s, 2);
      s += __shfl_xor(s, 4);
      if ((tid & 7) == 0) ksq[tk] = s;
      // commit V^T [d][t]: repack 4 transposed u32 -> 2x ds_write_b64
      uint2 LO, HI;
      LO.x = (vreg[0] & 0xffffu) | (vreg[1] << 16);
      LO.y = (vreg[2] & 0xffffu) | (vreg[3] << 16);
      HI.x = (vreg[0] >> 16) | (vreg[1] & 0xffff0000u);
      HI.y = (vreg[2] >> 16) | (vreg[3] & 0xffff0000u);
      *(uint2*)&Vt[(2 * d0) * 72 + tg4 * 4] = LO;
      *(uint2*)&Vt[(2 * d0 + 1) * 72 + tg4 * 4] = HI;
    }
    if (kt < ktmax) {  // prefetch kt+1 — latency overlaps this iteration's compute
      kreg = *(const uint4*)(base + 1024 + (size_t)((kt + 1) * 64 + tk) * 3072 + dck);
      const unsigned short* gv =
          base + 2048 + (size_t)((kt + 1) * 64 + tg4 * 4) * 3072 + 2 * d0;
#pragma unroll
      for (int s = 0; s < 4; s++)
        vreg[s] = *(const unsigned int*)(gv + (size_t)s * 3072);
    }
    __syncthreads();  // staging visible

    // S = Q K^T : wave's 16 q rows x 64 keys
    f32x4 accS[4] = {};
#pragma unroll
    for (int nt = 0; nt < 4; nt++) {
      const f16x8 bk0 = *(const f16x8*)&Kp[(nt * 16 + l15) * 72 + quad * 8];
      const f16x8 bk1 = *(const f16x8*)&Kp[(nt * 16 + l15) * 72 + 32 + quad * 8];
      accS[nt] = MFMA16(aq0, bk0, accS[nt]);
      accS[nt] = MFMA16(aq1, bk1, accS[nt]);
    }
    const int kdiff = kt * 64 - yb * 128;  // >=0 only on the two diagonal tiles
    const bool dz = (kdiff >= 0);
    float pval[4][4];
    float tmax[4] = {0.f, 0.f, 0.f, 0.f};  // scores >= 0
#pragma unroll
    for (int nt = 0; nt < 4; nt++) {
#pragma unroll
      for (int r = 0; r < 4; r++) {
        const int ql = w * 16 + quad * 4 + r;   // block-local q (0..127)
        const int tl = nt * 16 + l15;           // tile-local key (0..63)
        const float d = accS[nt][r];
        const float den = qsq[ql] + ksq[tl] - 2.f * d + 1e-6f;
        float s = d * d * __builtin_amdgcn_rcpf(den);
        if (dz && (kdiff + tl > ql)) s = -1e30f;
        pval[nt][r] = s;
        tmax[r] = fmaxf(tmax[r], s);
      }
    }
#pragma unroll
    for (int r = 0; r < 4; r++) {
      tmax[r] = fmaxf(tmax[r], __shfl_xor(tmax[r], 1));
      tmax[r] = fmaxf(tmax[r], __shfl_xor(tmax[r], 2));
      tmax[r] = fmaxf(tmax[r], __shfl_xor(tmax[r], 4));
      tmax[r] = fmaxf(tmax[r], __shfl_xor(tmax[r], 8));
    }
    float alpha[4];
#pragma unroll
    for (int r = 0; r < 4; r++) {
      const float mn = fmaxf(m_r[r], tmax[r]);
      alpha[r] = __expf(m_r[r] - mn);
      m_r[r] = mn;
    }
#pragma unroll
    for (int nt = 0; nt < 4; nt++)
#pragma unroll
      for (int r = 0; r < 4; r++)
        pval[nt][r] = __expf(pval[nt][r] - m_r[r]);
#pragma unroll
    for (int r = 0; r < 4; r++) {
      float su = pval[0][r] + pval[1][r] + pval[2][r] + pval[3][r];
      su += __shfl_xor(su, 1);
      su += __shfl_xor(su, 2);
      su += __shfl_xor(su, 4);
      su += __shfl_xor(su, 8);
      l_r[r] = l_r[r] * alpha[r] + su;
    }
#pragma unroll
    for (int nt = 0; nt < 4; nt++)
#pragma unroll
      for (int r = 0; r < 4; r++)
        Pl[(w * 16 + quad * 4 + r) * 72 + nt * 16 + l15] = f2h(pval[nt][r]);
    if (l15 == 0) {
#pragma unroll
      for (int r = 0; r < 4; r++) bcast[w * 16 + quad * 4 + r] = alpha[r];
    }
    __syncthreads();  // Pl/bcast visible

    // rescale O^T (per-lane uniform alpha) then O^T += V^T P^T
    const float am = bcast[w * 16 + l15];
#pragma unroll
    for (int i = 0; i < 4; i++) {
      accO[i][0] *= am; accO[i][1] *= am; accO[i][2] *= am; accO[i][3] *= am;
    }
    const f16x8 bp0 = *(const f16x8*)&Pl[(w * 16 + l15) * 72 + quad * 8];
    const f16x8 bp1 = *(const f16x8*)&Pl[(w * 16 + l15) * 72 + 32 + quad * 8];
#pragma unroll
    for (int i = 0; i < 4; i++) {
      const f16x8 av0 = *(const f16x8*)&Vt[(i * 16 + l15) * 72 + quad * 8];
      const f16x8 av1 = *(const f16x8*)&Vt[(i * 16 + l15) * 72 + 32 + quad * 8];
      accO[i] = MFMA16(av0, bp0, accO[i]);
      accO[i] = MFMA16(av1, bp1, accO[i]);
    }
  }

  // finalize: divide by l, transpose O^T -> O through LDS (Qp reuse), 16B stores
  __syncthreads();  // last PV's bcast reads complete (WAR)
  if (l15 == 0) {
#pragma unroll
    for (int r = 0; r < 4; r++) bcast[w * 16 + quad * 4 + r] = l_r[r];
  }
  __syncthreads();
  const float linv = 1.0f / bcast[w * 16 + l15];
#pragma unroll
  for (int i = 0; i < 4; i++)
#pragma unroll
    for (int r = 0; r < 4; r++)
      Qp[(w * 16 + l15) * 72 + i * 16 + quad * 4 + r] = f2h(accO[i][r] * linv);
  __syncthreads();
  {
    uint4 o0 = *(const uint4*)&Qp[t2 * 72 + dc];
    uint4 o1 = *(const uint4*)&Qp[t2 * 72 + dc + 8];
    unsigned short* g = outp + (size_t)(b * TSEQ + yb * 128 + t2) * 1024 + h * 64 + dc;
    *(uint4*)g = o0;
    *(uint4*)(g + 8) = o1;
  }
}

extern "C" void kernel_launch(void* const* d_in, const int* in_sizes, int n_in,
                              void* d_out, int out_size, void* d_ws, size_t ws_size,
                              hipStream_t stream) {
  (void)in_sizes; (void)n_in; (void)out_size; (void)ws_size;
  const float* x     = (const float*)d_in[0];  // [2,2048,1024] fp32
  const float* w_qkv = (const float*)d_in[1];  // [1024,3072]   fp32
  const float* b_qkv = (const float*)d_in[2];  // [3072]        fp32
  const float* w_out = (const float*)d_in[3];  // [1024,1024]   fp32
  const float* b_out = (const float*)d_in[4];  // [1024]        fp32
  float* out = (float*)d_out;                  // [2,2048,1024] fp32

  unsigned short* wqkvT  = (unsigned short*)d_ws;                    // [3072][1024] fp16
  unsigned short* woT    = wqkvT + (size_t)3072 * 1024;              // [1024][1024] fp16
  unsigned short* qkvws  = woT + (size_t)1024 * 1024;                // [4096][3072] fp16
  unsigned short* xh     = qkvws + (size_t)4096 * 3072;              // [4096][1024] fp16
  unsigned short* attnws = xh;  // alias: xh dead after gemm1, attnws born at yat_attn

  cvt_x<<<dim3(4096 * 1024 / (256 * 8)), 256, 0, stream>>>(x, xh);
  transpose_w<<<dim3(3072 / 32, 1024 / 32), dim3(32, 8), 0, stream>>>(w_qkv, wqkvT, 1024, 3072);
  transpose_w<<<dim3(1024 / 32, 1024 / 32), dim3(32, 8), 0, stream>>>(w_out, woT, 1024, 1024);
  gemm_bt<128, false><<<dim3(3072 / 128, 4096 / 128), 256, 0, stream>>>(xh, wqkvT, b_qkv, qkvws, 3072, 1024);
  yat_attn<<<dim3(BATCH * 16, 16), 512, 0, stream>>>(qkvws, attnws);
  gemm_bt<64, true><<<dim3(1024 / 64, 4096 / 128), 256, 0, stream>>>(attnws, woT, b_out, out, 1024, 1024);
}

// Round 9
// 205.503 us; speedup vs baseline: 1.1037x; 1.1037x over previous
//
#include <hip/hip_runtime.h>
#include <stdint.h>

// YatCausalAttention on MI355X (gfx950).
// Inputs FP32, output FP32. Intermediates FP16 via f16 MFMA, fp32 accum.
// Pipeline: cvt_x -> transpose+cvt weights -> gemm<128>(x,wqkvT) -> qkv(fp16)
//           -> yat flash attention (64-q blocks) -> gemm<64> -> out.
// ws (fp16 elems): wqkvT 3072*1024 | woT 1024*1024 | qkv 4096*3072 | xh/attn 4096*1024 = 40 MB
// R9 = R8 with the DPP ctrl made a template constant (compile fix only):
// (a) P row-sums via ones-MFMA (l lands in O^T lane layout as a register;
// kills 16 ds_swizzles/iter + final bcast); (b) max-reduction via DPP row_ror
// (VALU-rate, no LDS latency); (c) Q-frags hoisted. GEMMs unchanged.

#define TSEQ 2048
#define BATCH 2

typedef _Float16 f16x8 __attribute__((ext_vector_type(8)));
typedef float f32x4 __attribute__((ext_vector_type(4)));

#define MFMA16(a, b, c) __builtin_amdgcn_mfma_f32_16x16x32_f16(a, b, c, 0, 0, 0)

__device__ __forceinline__ unsigned short f2h(float f) {
  union { _Float16 h; unsigned short u; } v;
  v.h = (_Float16)f;
  return v.u;
}
__device__ __forceinline__ float h2f(unsigned short u) {
  union { unsigned short u; _Float16 h; } v;
  v.u = u;
  return (float)v.h;
}
__device__ __forceinline__ unsigned int pack2h(float lo, float hi) {
  return (unsigned int)f2h(lo) | ((unsigned int)f2h(hi) << 16);
}
__device__ __forceinline__ float sumsq_u32(unsigned int u) {
  float lo = h2f(u & 0xffffu);
  float hi = h2f(u >> 16);
  return lo * lo + hi * hi;
}
__device__ __forceinline__ void async_ld16(const void* g, const void* l) {
  __builtin_amdgcn_global_load_lds((const __attribute__((address_space(1))) void*)g,
                                   (__attribute__((address_space(3))) void*)l,
                                   16, 0, 0);
}
// one DPP row_ror step with compile-time control (builtin demands an ICE)
template <int CTRL>
__device__ __forceinline__ float dpp_max_step(float x) {
  float y = __uint_as_float((unsigned)__builtin_amdgcn_update_dpp(
      0, (int)__float_as_uint(x), CTRL, 0xf, 0xf, true));
  return fmaxf(x, y);
}
// max-reduce over the 16-lane DPP row via row_ror 1,2,4,8 (pure VALU, no LDS)
__device__ __forceinline__ float dpp_row_max(float x) {
  x = dpp_max_step<0x121>(x);  // ROW_ROR:1
  x = dpp_max_step<0x122>(x);  // ROW_ROR:2
  x = dpp_max_step<0x124>(x);  // ROW_ROR:4
  x = dpp_max_step<0x128>(x);  // ROW_ROR:8
  return x;
}

// ---------------- x: fp32 -> fp16, 8 elems/thread ----------------
__global__ __launch_bounds__(256) void cvt_x(const float* __restrict__ src,
                                             unsigned short* __restrict__ dst) {
  const int i = (blockIdx.x * 256 + threadIdx.x) * 8;
  const float4 a = *(const float4*)(src + i);
  const float4 b = *(const float4*)(src + i + 4);
  uint4 o;
  o.x = pack2h(a.x, a.y); o.y = pack2h(a.z, a.w);
  o.z = pack2h(b.x, b.y); o.w = pack2h(b.z, b.w);
  *(uint4*)(dst + i) = o;
}

// ------------- weight transpose+convert: src[K][N] (fp32) -> dst[N][K] (fp16) -------------
__global__ __launch_bounds__(256) void transpose_w(const float* __restrict__ src,
                                                   unsigned short* __restrict__ dst,
                                                   int K, int N) {
  __shared__ unsigned short tile[32][33];
  const int tx = threadIdx.x, ty = threadIdx.y;           // (32,8)
  const int nb = blockIdx.x * 32, kb = blockIdx.y * 32;
#pragma unroll
  for (int i = 0; i < 4; i++)
    tile[ty + 8 * i][tx] = f2h(src[(size_t)(kb + ty + 8 * i) * N + nb + tx]);
  __syncthreads();
#pragma unroll
  for (int i = 0; i < 4; i++)
    dst[(size_t)(nb + ty + 8 * i) * K + kb + tx] = tile[tx][ty + 8 * i];
}

// ------------- C[M][TN-tile] = A[M][K] * Bt[N][K]^T + bias[N]  (fp16 in, fp32 acc) -------------
// 128xTN tile, BK=32, global_load_lds width=16. TN=128: wave=64x64 (4x4 MFMA).
// TN=64: wave=64x32 (4x2 MFMA), grid doubles -> 2 blocks/CU for small-N gemm.
template <int TN, bool OUT_F32>
__global__ __launch_bounds__(256) void gemm_bt(const unsigned short* __restrict__ A,
                                               const unsigned short* __restrict__ Bt,
                                               const float* __restrict__ bias,
                                               void* __restrict__ Cp,
                                               int N, int K) {
  __shared__ __attribute__((aligned(16))) unsigned short Atile[128 * 32];
  __shared__ __attribute__((aligned(16))) unsigned short Btile[TN * 32];
  constexpr int NJ = TN / 32;  // 16-col tiles per wave
  const int tid = threadIdx.x;
  const int w = tid >> 6, lane = tid & 63;
  const int quad = lane >> 4, l15 = lane & 15;
  const int m0 = blockIdx.y * 128, n0 = blockIdx.x * TN;
  const int wr = w >> 1, wc = w & 1;
  const int nwc = wc * (TN / 2);
  f32x4 acc[4][NJ] = {};
  for (int kt = 0; kt < K; kt += 32) {
    __syncthreads();  // previous iteration's fragment reads complete
#pragma unroll
    for (int it = 0; it < 2; it++) {      // A: 128 rows
      const int c = it * 256 + tid;       // chunk: row = c>>2, 8-elem k-chunk = c&3
      async_ld16(A + (size_t)(m0 + (c >> 2)) * K + kt + (c & 3) * 8,
                 &Atile[(size_t)(it * 256 + w * 64) * 8]);   // wave-uniform LDS base
    }
#pragma unroll
    for (int it = 0; it < TN / 64; it++) {  // B: TN rows
      const int c = it * 256 + tid;
      async_ld16(Bt + (size_t)(n0 + (c >> 2)) * K + kt + (c & 3) * 8,
                 &Btile[(size_t)(it * 256 + w * 64) * 8]);
    }
    __syncthreads();  // vmcnt(0) drain lands the async copies
    f16x8 af[4], bfr[NJ];
#pragma unroll
    for (int i = 0; i < 4; i++)
      af[i] = *(const f16x8*)&Atile[(wr * 64 + i * 16 + l15) * 32 + quad * 8];
#pragma unroll
    for (int j = 0; j < NJ; j++)
      bfr[j] = *(const f16x8*)&Btile[(nwc + j * 16 + l15) * 32 + quad * 8];
#pragma unroll
    for (int i = 0; i < 4; i++)
#pragma unroll
      for (int j = 0; j < NJ; j++)
        acc[i][j] = MFMA16(af[i], bfr[j], acc[i][j]);
  }
  // epilogue: C/D layout col=lane&15, row=quad*4+reg
#pragma unroll
  for (int j = 0; j < NJ; j++) {
    const int n = n0 + nwc + j * 16 + l15;
    const float bv = bias[n];
#pragma unroll
    for (int i = 0; i < 4; i++) {
      const int mb = m0 + wr * 64 + i * 16 + quad * 4;
#pragma unroll
      for (int r = 0; r < 4; r++) {
        if constexpr (OUT_F32)
          ((float*)Cp)[(size_t)(mb + r) * N + n] = acc[i][j][r] + bv;
        else
          ((unsigned short*)Cp)[(size_t)(mb + r) * N + n] = f2h(acc[i][j][r] + bv);
      }
    }
  }
}

// ---------------- Yat causal flash attention (fp16 in/out, fp32 math) ----------------
// grid: (B*H, 32). Block 256 = 4 waves; wave w owns q rows [16w,16w+16).
// score = dot^2 * rcp(qsq + ksq - 2 dot + 1e-6), causal, online softmax.
// PV as O^T = V^T * P^T (rescale per-lane uniform). K/V prefetched 1 iter
// ahead. Row-sums of P via ones-MFMA (l in O^T layout, register). Max via DPP.
__global__ __launch_bounds__(256, 4) void yat_attn(const unsigned short* __restrict__ qkv,
                                                   unsigned short* __restrict__ outp) {
  __shared__ __attribute__((aligned(16))) unsigned short Qp[64 * 72];  // [q][d] pad 72
  __shared__ __attribute__((aligned(16))) unsigned short Kp[64 * 72];  // [t][d]
  __shared__ __attribute__((aligned(16))) unsigned short Vt[64 * 72];  // [d][t]
  __shared__ __attribute__((aligned(16))) unsigned short Pl[64 * 72];  // [q][t]
  __shared__ float qsq[64], ksq[64], bcast[64];
  const int tid = threadIdx.x;
  const int w = tid >> 6, lane = tid & 63;
  const int quad = lane >> 4, l15 = lane & 15;
  const int bh = blockIdx.x, b = bh >> 4, h = bh & 15;
  // dispatch-round-aware qt map: per y-octave per CU; iteration sums uniform.
  const int y = blockIdx.y;
  const int qt = (y < 8) ? 31 - y : (y < 16) ? y - 8 : (y < 24) ? 39 - y : y - 16;
  const unsigned short* base = qkv + (size_t)b * TSEQ * 3072 + h * 64;
  const int t = tid >> 2, dc = (tid & 3) * 16;   // K/Q staging: row t, 16 d's
  const int d0 = tid & 31, tg8 = tid >> 5;       // V staging: 2 d-rows, 8 t's

  {  // stage Q tile + row sums of squares (same rounded values MFMA sees)
    const unsigned short* g = base + (size_t)(qt * 64 + t) * 3072 + dc;
    uint4 v0 = *(const uint4*)g;
    uint4 v1 = *(const uint4*)(g + 8);
    *(uint4*)&Qp[t * 72 + dc] = v0;
    *(uint4*)&Qp[t * 72 + dc + 8] = v1;
    float s = sumsq_u32(v0.x) + sumsq_u32(v0.y) + sumsq_u32(v0.z) + sumsq_u32(v0.w) +
              sumsq_u32(v1.x) + sumsq_u32(v1.y) + sumsq_u32(v1.z) + sumsq_u32(v1.w);
    s += __shfl_xor(s, 1);
    s += __shfl_xor(s, 2);
    if ((tid & 3) == 0) qsq[t] = s;
  }
  __syncthreads();
  // hoisted loop-invariant Q fragments (wave w, q rows 16w..16w+16)
  const f16x8 aq0 = *(const f16x8*)&Qp[(w * 16 + l15) * 72 + quad * 8];
  const f16x8 aq1 = *(const f16x8*)&Qp[(w * 16 + l15) * 72 + 32 + quad * 8];
  const f16x8 onesf = {(_Float16)1.f, (_Float16)1.f, (_Float16)1.f, (_Float16)1.f,
                       (_Float16)1.f, (_Float16)1.f, (_Float16)1.f, (_Float16)1.f};

  f32x4 accO[4] = {};                    // O^T: lane q = 16w+l15, d = 16i+quad*4+r
  float m_r[4] = {0.f, 0.f, 0.f, 0.f};   // scores >= 0 so 0 is a valid init max
  float l_acc = 0.f;                     // l in O^T layout: lane q = 16w+l15

  // prefetch kt=0 K/V into registers
  uint4 kreg0, kreg1;
  unsigned int vreg[8];
  {
    const unsigned short* gk = base + 1024 + (size_t)t * 3072 + dc;
    kreg0 = *(const uint4*)gk;
    kreg1 = *(const uint4*)(gk + 8);
    const unsigned short* gv = base + 2048 + (size_t)(tg8 * 8) * 3072 + 2 * d0;
#pragma unroll
    for (int s = 0; s < 8; s++)
      vreg[s] = *(const unsigned int*)(gv + (size_t)s * 3072);
  }

  for (int kt = 0; kt <= qt; kt++) {
    __syncthreads();  // prev iteration's Kp/Vt/Pl reads complete
    {  // commit staged K [t][d] + ksq from registers
      *(uint4*)&Kp[t * 72 + dc] = kreg0;
      *(uint4*)&Kp[t * 72 + dc + 8] = kreg1;
      float s = sumsq_u32(kreg0.x) + sumsq_u32(kreg0.y) + sumsq_u32(kreg0.z) +
                sumsq_u32(kreg0.w) + sumsq_u32(kreg1.x) + sumsq_u32(kreg1.y) +
                sumsq_u32(kreg1.z) + sumsq_u32(kreg1.w);
      s += __shfl_xor(s, 1);
      s += __shfl_xor(s, 2);
      if ((tid & 3) == 0) ksq[t] = s;
      // commit V^T [d][t]: repack 8 transposed u32 -> 2x ds_write_b128
      uint4 LO, HI;
      LO.x = (vreg[0] & 0xffffu) | (vreg[1] << 16);
      LO.y = (vreg[2] & 0xffffu) | (vreg[3] << 16);
      LO.z = (vreg[4] & 0xffffu) | (vreg[5] << 16);
      LO.w = (vreg[6] & 0xffffu) | (vreg[7] << 16);
      HI.x = (vreg[0] >> 16) | (vreg[1] & 0xffff0000u);
      HI.y = (vreg[2] >> 16) | (vreg[3] & 0xffff0000u);
      HI.z = (vreg[4] >> 16) | (vreg[5] & 0xffff0000u);
      HI.w = (vreg[6] >> 16) | (vreg[7] & 0xffff0000u);
      *(uint4*)&Vt[(2 * d0) * 72 + tg8 * 8] = LO;
      *(uint4*)&Vt[(2 * d0 + 1) * 72 + tg8 * 8] = HI;
    }
    if (kt < qt) {  // prefetch kt+1 — latency overlaps this iteration's compute
      const unsigned short* gk = base + 1024 + (size_t)((kt + 1) * 64 + t) * 3072 + dc;
      kreg0 = *(const uint4*)gk;
      kreg1 = *(const uint4*)(gk + 8);
      const unsigned short* gv =
          base + 2048 + (size_t)((kt + 1) * 64 + tg8 * 8) * 3072 + 2 * d0;
#pragma unroll
      for (int s = 0; s < 8; s++)
        vreg[s] = *(const unsigned int*)(gv + (size_t)s * 3072);
    }
    __syncthreads();  // staging visible

    // S = Q K^T : wave's 16 q rows x 64 keys
    f32x4 accS[4] = {};
#pragma unroll
    for (int nt = 0; nt < 4; nt++) {
      const f16x8 bk0 = *(const f16x8*)&Kp[(nt * 16 + l15) * 72 + quad * 8];
      const f16x8 bk1 = *(const f16x8*)&Kp[(nt * 16 + l15) * 72 + 32 + quad * 8];
      accS[nt] = MFMA16(aq0, bk0, accS[nt]);
      accS[nt] = MFMA16(aq1, bk1, accS[nt]);
    }
    const bool diag = (kt == qt);
    float pval[4][4];
    float tmax[4] = {0.f, 0.f, 0.f, 0.f};  // scores >= 0
#pragma unroll
    for (int nt = 0; nt < 4; nt++) {
#pragma unroll
      for (int r = 0; r < 4; r++) {
        const int ql = w * 16 + quad * 4 + r;   // C-layout row
        const int tl = nt * 16 + l15;           // C-layout col
        const float d = accS[nt][r];
        const float den = qsq[ql] + ksq[tl] - 2.f * d + 1e-6f;
        float s = d * d * __builtin_amdgcn_rcpf(den);
        if (diag && tl > ql) s = -1e30f;
        pval[nt][r] = s;
        tmax[r] = fmaxf(tmax[r], s);
      }
    }
    float alpha[4];
#pragma unroll
    for (int r = 0; r < 4; r++) {
      const float mn = fmaxf(m_r[r], dpp_row_max(tmax[r]));  // DPP row_ror max
      alpha[r] = __expf(m_r[r] - mn);
      m_r[r] = mn;
    }
#pragma unroll
    for (int nt = 0; nt < 4; nt++)
#pragma unroll
      for (int r = 0; r < 4; r++)
        Pl[(w * 16 + quad * 4 + r) * 72 + nt * 16 + l15] =
            f2h(__expf(pval[nt][r] - m_r[r]));
    if (l15 == 0) {
#pragma unroll
      for (int r = 0; r < 4; r++) bcast[w * 16 + quad * 4 + r] = alpha[r];
    }
    __syncthreads();  // Pl/bcast visible

    // rescale O^T (per-lane uniform alpha), l-sum via ones-MFMA, O^T += V^T P^T
    const float am = bcast[w * 16 + l15];
#pragma unroll
    for (int i = 0; i < 4; i++) {
      accO[i][0] *= am; accO[i][1] *= am; accO[i][2] *= am; accO[i][3] *= am;
    }
    const f16x8 bp0 = *(const f16x8*)&Pl[(w * 16 + l15) * 72 + quad * 8];
    const f16x8 bp1 = *(const f16x8*)&Pl[(w * 16 + l15) * 72 + 32 + quad * 8];
    f32x4 accL = {};  // D = ones * P^T -> col=l15=q, rows identical = sum_t P[q][t]
    accL = MFMA16(onesf, bp0, accL);
    accL = MFMA16(onesf, bp1, accL);
#pragma unroll
    for (int i = 0; i < 4; i++) {
      const f16x8 av0 = *(const f16x8*)&Vt[(i * 16 + l15) * 72 + quad * 8];
      const f16x8 av1 = *(const f16x8*)&Vt[(i * 16 + l15) * 72 + 32 + quad * 8];
      accO[i] = MFMA16(av0, bp0, accO[i]);
      accO[i] = MFMA16(av1, bp1, accO[i]);
    }
    l_acc = l_acc * am + accL[0];
  }

  // finalize: divide by l (already in O^T lane layout), transpose through Qp, store
  __syncthreads();  // all waves' last Pl/Vt reads complete before Qp overwrite
  const float linv = 1.0f / l_acc;
#pragma unroll
  for (int i = 0; i < 4; i++)
#pragma unroll
    for (int r = 0; r < 4; r++)
      Qp[(w * 16 + l15) * 72 + i * 16 + quad * 4 + r] = f2h(accO[i][r] * linv);
  __syncthreads();
  {
    uint4 o0 = *(const uint4*)&Qp[t * 72 + dc];
    uint4 o1 = *(const uint4*)&Qp[t * 72 + dc + 8];
    unsigned short* g = outp + (size_t)(b * TSEQ + qt * 64 + t) * 1024 + h * 64 + dc;
    *(uint4*)g = o0;
    *(uint4*)(g + 8) = o1;
  }
}

extern "C" void kernel_launch(void* const* d_in, const int* in_sizes, int n_in,
                              void* d_out, int out_size, void* d_ws, size_t ws_size,
                              hipStream_t stream) {
  (void)in_sizes; (void)n_in; (void)out_size; (void)ws_size;
  const float* x     = (const float*)d_in[0];  // [2,2048,1024] fp32
  const float* w_qkv = (const float*)d_in[1];  // [1024,3072]   fp32
  const float* b_qkv = (const float*)d_in[2];  // [3072]        fp32
  const float* w_out = (const float*)d_in[3];  // [1024,1024]   fp32
  const float* b_out = (const float*)d_in[4];  // [1024]        fp32
  float* out = (float*)d_out;                  // [2,2048,1024] fp32

  unsigned short* wqkvT  = (unsigned short*)d_ws;                    // [3072][1024] fp16
  unsigned short* woT    = wqkvT + (size_t)3072 * 1024;              // [1024][1024] fp16
  unsigned short* qkvws  = woT + (size_t)1024 * 1024;                // [4096][3072] fp16
  unsigned short* xh     = qkvws + (size_t)4096 * 3072;              // [4096][1024] fp16
  unsigned short* attnws = xh;  // alias: xh dead after gemm1, attnws born at yat_attn

  cvt_x<<<dim3(4096 * 1024 / (256 * 8)), 256, 0, stream>>>(x, xh);
  transpose_w<<<dim3(3072 / 32, 1024 / 32), dim3(32, 8), 0, stream>>>(w_qkv, wqkvT, 1024, 3072);
  transpose_w<<<dim3(1024 / 32, 1024 / 32), dim3(32, 8), 0, stream>>>(w_out, woT, 1024, 1024);
  gemm_bt<128, false><<<dim3(3072 / 128, 4096 / 128), 256, 0, stream>>>(xh, wqkvT, b_qkv, qkvws, 3072, 1024);
  yat_attn<<<dim3(BATCH * 16, 32), 256, 0, stream>>>(qkvws, attnws);
  gemm_bt<64, true><<<dim3(1024 / 64, 4096 / 128), 256, 0, stream>>>(attnws, woT, b_out, out, 1024, 1024);
}